// Round 13
// baseline (652.997 us; speedup 1.0000x reference)
//
#include <hip/hip_runtime.h>

typedef _Float16 f16;
typedef _Float16 f16x8 __attribute__((ext_vector_type(8)));
typedef _Float16 f16x4 __attribute__((ext_vector_type(4)));
typedef float    f32x4 __attribute__((ext_vector_type(4)));

#define H  128
#define G3 384
#define AH 36
#define PADW 136   // padded LDS row: 136 f16 = 272B

// v_rcp_f32 (~1 ulp) — proven R10.
__device__ __forceinline__ float sigmoidf_(float x){
  return __builtin_amdgcn_rcpf(1.f + __expf(-x));
}
__device__ __forceinline__ float tanhf_(float x){
  return fmaf(2.f, __builtin_amdgcn_rcpf(1.f + __expf(-2.f*x)), -1.f);
}

// LDS-only barrier: global prefetch loads stay in flight across it.
__device__ __forceinline__ void lds_sync(){
  asm volatile("s_waitcnt lgkmcnt(0)" ::: "memory");
  __builtin_amdgcn_s_barrier();
  asm volatile("" ::: "memory");
}

// ---------------- prep: weights fp32 -> fp16, lengths ----------------
__global__ void prep_weights(const float* __restrict__ a, const float* __restrict__ b,
                             const float* __restrict__ c, const float* __restrict__ d,
                             f16* __restrict__ dst)
{
  int i = blockIdx.x * 256 + threadIdx.x;
  if (i >= 4 * G3 * H) return;
  int m = i / (G3 * H), j = i % (G3 * H);
  const float* s = (m == 0) ? a : (m == 1) ? b : (m == 2) ? c : d;
  dst[i] = (f16)s[j];
}

__global__ void prep_len(const int* __restrict__ mask, int* __restrict__ len, int T, int B)
{
  int b = blockIdx.x * 256 + threadIdx.x;
  if (b >= B) return;
  int s = 0;
  for (int t = 0; t < T; ++t) s += (mask[(size_t)b * T + t] > 0);
  len[b] = s;
}

// ---------------- dual-recurrence scan (v10) ----------------
// One block = 32 batch rows = TWO independent 16-row recurrences (A,B) sharing
// weight registers. Chain B's ds_reads/MFMAs overlap chain A's latency; gates
// of A overlap MFMA tail of B. 8 waves; wave w owns gate cols [16w,16w+16)
// for BOTH tiles.
template<bool AUG>
__global__ __launch_bounds__(512)
__attribute__((amdgpu_waves_per_eu(2, 2)))
void scan_kernel(const float* __restrict__ xf32,  // GRU input  [B,T,H] f32
                 const f16*   __restrict__ xf16,  // AUGRU input (hist) [B,T,H] f16
                 const f16*   __restrict__ Wih,   // [3H][H] f16
                 const f16*   __restrict__ Whh,   // [3H][H] f16
                 const float* __restrict__ bih,
                 const float* __restrict__ bhh,
                 const float* __restrict__ att,   // [B,T] (AUG)
                 const int*   __restrict__ len,   // [B]   (AUG)
                 f16*         __restrict__ histo, // [B,T,H] f16 (GRU)
                 float*       __restrict__ outp,  // [B,H]       (AUG)
                 int T)
{
  __shared__ f16 xsA[2][16 * PADW], hsA[2][16 * PADW];
  __shared__ f16 xsB[2][16 * PADW], hsB[2][16 * PADW];

  const int tid = threadIdx.x;
  const int w   = tid >> 6;
  const int l   = tid & 63;
  const int l16 = l & 15;
  const int lhi = l >> 4;
  const int b0  = blockIdx.x * 32;          // tile A rows b0.., tile B rows b0+16..
  const int colb = w * 16;
  const int c4   = colb + lhi * 4;
  const int srow = tid >> 5, cc = tid & 31;

  // Weight fragments (24 x f16x8 = 96 regs), pinned. Shared by both tiles.
  f16x8 wih[3][4], whh[3][4];
  #pragma unroll
  for (int g = 0; g < 3; ++g)
    #pragma unroll
    for (int q = 0; q < 4; ++q) {
      int off = (g * H + colb + l16) * H + q * 32 + lhi * 8;
      wih[g][q] = *(const f16x8*)(Wih + off);
      whh[g][q] = *(const f16x8*)(Whh + off);
    }
  #pragma unroll
  for (int g = 0; g < 3; ++g)
    #pragma unroll
    for (int q = 0; q < 4; ++q)
      asm volatile("" : "+v"(wih[g][q]), "+v"(whh[g][q]));

  // bias C-inits
  f32x4 bRs = *(const f32x4*)(bih + c4);
  { f32x4 t2 = *(const f32x4*)(bhh + c4);     bRs += t2; }
  f32x4 bZs = *(const f32x4*)(bih + H + c4);
  { f32x4 t2 = *(const f32x4*)(bhh + H + c4); bZs += t2; }
  f32x4 bXn = *(const f32x4*)(bih + 2*H + c4);
  f32x4 bHn = *(const f32x4*)(bhh + 2*H + c4);

  float holdA[4] = {0.f,0.f,0.f,0.f}, holdB[4] = {0.f,0.f,0.f,0.f};
  int len_lA = 0, len_lB = 0;
  if (AUG) { len_lA = len[b0 + l16]; len_lB = len[b0 + 16 + l16]; }

  // hoisted LDS pointers (compile-time bases differ by constants; compiler folds)
  const f16* xrdA0 = &xsA[0][l16*PADW + lhi*8];
  const f16* xrdA1 = &xsA[1][l16*PADW + lhi*8];
  const f16* hrdA0 = &hsA[0][l16*PADW + lhi*8];
  const f16* hrdA1 = &hsA[1][l16*PADW + lhi*8];
  f16* hwrA0 = &hsA[0][l16*PADW + c4];
  f16* hwrA1 = &hsA[1][l16*PADW + c4];
  f16* xstA0 = &xsA[0][srow*PADW + cc*4];
  f16* xstA1 = &xsA[1][srow*PADW + cc*4];
  const f16* xrdB0 = &xsB[0][l16*PADW + lhi*8];
  const f16* xrdB1 = &xsB[1][l16*PADW + lhi*8];
  const f16* hrdB0 = &hsB[0][l16*PADW + lhi*8];
  const f16* hrdB1 = &hsB[1][l16*PADW + lhi*8];
  f16* hwrB0 = &hsB[0][l16*PADW + c4];
  f16* hwrB1 = &hsB[1][l16*PADW + c4];
  f16* xstB0 = &xsB[0][srow*PADW + cc*4];
  f16* xstB1 = &xsB[1][srow*PADW + cc*4];

  // running global pointers
  const float* pxA32_A = xf32 ? (xf32 + ((size_t)(b0 + srow)      * T) * H + cc*4) : nullptr;
  const float* pxA32_B = xf32 ? (xf32 + ((size_t)(b0 + 16 + srow) * T) * H + cc*4) : nullptr;
  const f16*   pxA16_A = xf16 ? (xf16 + ((size_t)(b0 + srow)      * T) * H + cc*4) : nullptr;
  const f16*   pxA16_B = xf16 ? (xf16 + ((size_t)(b0 + 16 + srow) * T) * H + cc*4) : nullptr;
  const float* attBA = AUG ? (att + (size_t)(b0 + l16) * T)      : nullptr;
  const float* attBB = AUG ? (att + (size_t)(b0 + 16 + l16) * T) : nullptr;
  f16* histpA = (!AUG && histo) ? (histo + ((size_t)(b0 + l16)      * T) * H + c4) : nullptr;
  f16* histpB = (!AUG && histo) ? (histo + ((size_t)(b0 + 16 + l16) * T) * H + c4) : nullptr;
  float* outppA = AUG ? (outp + (size_t)(b0 + l16)      * H + c4) : nullptr;
  float* outppB = AUG ? (outp + (size_t)(b0 + 16 + l16) * H + c4) : nullptr;

  // prologue: zero h bufs, stage x_0 (A,B), prefetch x_1, att
  {
    f16x4 z4 = {(f16)0,(f16)0,(f16)0,(f16)0};
    *(f16x4*)(&hsA[0][srow*PADW + cc*4]) = z4;
    *(f16x4*)(&hsB[0][srow*PADW + cc*4]) = z4;
    if (AUG) {
      *(f16x4*)xstA0 = *(const f16x4*)(pxA16_A);
      *(f16x4*)xstB0 = *(const f16x4*)(pxA16_B);
    } else {
      f32x4 va = *(const f32x4*)(pxA32_A);
      f32x4 vb = *(const f32x4*)(pxA32_B);
      f16x4 ha = {(f16)va.x,(f16)va.y,(f16)va.z,(f16)va.w};
      f16x4 hb = {(f16)vb.x,(f16)vb.y,(f16)vb.z,(f16)vb.w};
      *(f16x4*)xstA0 = ha;
      *(f16x4*)xstB0 = hb;
    }
  }
  f32x4 Pa32A={0,0,0,0}, Pb32A={0,0,0,0}, Pa32B={0,0,0,0}, Pb32B={0,0,0,0};
  f16x4 Pa16A={(f16)0,(f16)0,(f16)0,(f16)0}, Pb16A=Pa16A, Pa16B=Pa16A, Pb16B=Pa16A;
  float AaA=0.f, AbA=0.f, AaB=0.f, AbB=0.f;
  if (AUG) {
    if (T > 1) { Pa16A = *(const f16x4*)(pxA16_A + H); Pa16B = *(const f16x4*)(pxA16_B + H); }
    AaA = attBA[0]; AaB = attBB[0];
    if (T > 1) { AbA = attBA[1]; AbB = attBB[1]; }
  } else {
    if (T > 1) { Pa32A = *(const f32x4*)(pxA32_A + H); Pa32B = *(const f32x4*)(pxA32_B + H); }
  }
  const float* pxEA32 = pxA32_A ? pxA32_A + 2*H : nullptr;
  const float* pxOA32 = pxA32_A ? pxA32_A + 3*H : nullptr;
  const float* pxEB32 = pxA32_B ? pxA32_B + 2*H : nullptr;
  const float* pxOB32 = pxA32_B ? pxA32_B + 3*H : nullptr;
  const f16*   pxEA16 = pxA16_A ? pxA16_A + 2*H : nullptr;
  const f16*   pxOA16 = pxA16_A ? pxA16_A + 3*H : nullptr;
  const f16*   pxEB16 = pxA16_B ? pxA16_B + 2*H : nullptr;
  const f16*   pxOB16 = pxA16_B ? pxA16_B + 3*H : nullptr;
  lds_sync();

// All internal names suffixed (R3 lesson). Tile A's MFMAs issue first; tile B's
// frag reads + MFMAs overlap A's chain latency; then gates A, gates B.
#define STEP(t5v, XRDA_, HRDA_, HWRA_, XSTA_, XRDB_, HRDB_, HWRB_, XSTB_,      \
             PW32A, PL32A, PW16A, PL16A, AWA_,                                 \
             PW32B, PL32B, PW16B, PL16B, AWB_, PXA32, PXA16, PXB32, PXB16)     \
  {                                                                            \
    const int t5_ = (t5v);                                                     \
    float atA_ = 0.f, atB_ = 0.f;                                              \
    if (AUG) { atA_ = AWA_; atB_ = AWB_; }                                     \
    if (t5_ + 2 < T) {                                                         \
      if (AUG) {                                                               \
        PL16A = *(const f16x4*)(PXA16);  PXA16 += 2*H;                         \
        PL16B = *(const f16x4*)(PXB16);  PXB16 += 2*H;                         \
        AWA_ = attBA[t5_ + 2];  AWB_ = attBB[t5_ + 2];                         \
      } else {                                                                 \
        PL32A = *(const f32x4*)(PXA32);  PXA32 += 2*H;                         \
        PL32B = *(const f32x4*)(PXB32);  PXB32 += 2*H;                         \
      }                                                                        \
    }                                                                          \
    f16x8 xba_[4], hba_[4];                                                    \
    _Pragma("unroll")                                                          \
    for (int q = 0; q < 4; ++q) {                                              \
      xba_[q] = *(const f16x8*)(XRDA_ + q*32);                                 \
      hba_[q] = *(const f16x8*)(HRDA_ + q*32);                                 \
    }                                                                          \
    f32x4 aRA = bRs, aZA = bZs, aXnA = bXn, aHnA = bHn;                        \
    _Pragma("unroll")                                                          \
    for (int q = 0; q < 4; ++q) {                                              \
      aRA  = __builtin_amdgcn_mfma_f32_16x16x32_f16(wih[0][q], xba_[q], aRA, 0,0,0); \
      aZA  = __builtin_amdgcn_mfma_f32_16x16x32_f16(wih[1][q], xba_[q], aZA, 0,0,0); \
      aXnA = __builtin_amdgcn_mfma_f32_16x16x32_f16(wih[2][q], xba_[q], aXnA,0,0,0); \
      aHnA = __builtin_amdgcn_mfma_f32_16x16x32_f16(whh[2][q], hba_[q], aHnA,0,0,0); \
    }                                                                          \
    _Pragma("unroll")                                                          \
    for (int q = 0; q < 4; ++q) {                                              \
      aRA  = __builtin_amdgcn_mfma_f32_16x16x32_f16(whh[0][q], hba_[q], aRA, 0,0,0); \
      aZA  = __builtin_amdgcn_mfma_f32_16x16x32_f16(whh[1][q], hba_[q], aZA, 0,0,0); \
    }                                                                          \
    f16x8 xbb_[4], hbb_[4];                                                    \
    _Pragma("unroll")                                                          \
    for (int q = 0; q < 4; ++q) {                                              \
      xbb_[q] = *(const f16x8*)(XRDB_ + q*32);                                 \
      hbb_[q] = *(const f16x8*)(HRDB_ + q*32);                                 \
    }                                                                          \
    f32x4 aRB = bRs, aZB = bZs, aXnB = bXn, aHnB = bHn;                        \
    _Pragma("unroll")                                                          \
    for (int q = 0; q < 4; ++q) {                                              \
      aRB  = __builtin_amdgcn_mfma_f32_16x16x32_f16(wih[0][q], xbb_[q], aRB, 0,0,0); \
      aZB  = __builtin_amdgcn_mfma_f32_16x16x32_f16(wih[1][q], xbb_[q], aZB, 0,0,0); \
      aXnB = __builtin_amdgcn_mfma_f32_16x16x32_f16(wih[2][q], xbb_[q], aXnB,0,0,0); \
      aHnB = __builtin_amdgcn_mfma_f32_16x16x32_f16(whh[2][q], hbb_[q], aHnB,0,0,0); \
    }                                                                          \
    _Pragma("unroll")                                                          \
    for (int q = 0; q < 4; ++q) {                                              \
      aRB  = __builtin_amdgcn_mfma_f32_16x16x32_f16(whh[0][q], hbb_[q], aRB, 0,0,0); \
      aZB  = __builtin_amdgcn_mfma_f32_16x16x32_f16(whh[1][q], hbb_[q], aZB, 0,0,0); \
    }                                                                          \
    float hnA_[4];                                                             \
    _Pragma("unroll")                                                          \
    for (int i = 0; i < 4; ++i) {                                              \
      float r = sigmoidf_(aRA[i]);                                             \
      float z = sigmoidf_(aZA[i]);                                             \
      float n = tanhf_(aXnA[i] + r * aHnA[i]);                                 \
      float h;                                                                 \
      if (AUG) { float u = z * atA_; h = holdA[i] + u * (n - holdA[i]); }      \
      else     { h = n + z * (holdA[i] - n); }                                 \
      holdA[i] = h; hnA_[i] = h;                                               \
    }                                                                          \
    float hnB_[4];                                                             \
    _Pragma("unroll")                                                          \
    for (int i = 0; i < 4; ++i) {                                              \
      float r = sigmoidf_(aRB[i]);                                             \
      float z = sigmoidf_(aZB[i]);                                             \
      float n = tanhf_(aXnB[i] + r * aHnB[i]);                                 \
      float h;                                                                 \
      if (AUG) { float u = z * atB_; h = holdB[i] + u * (n - holdB[i]); }      \
      else     { h = n + z * (holdB[i] - n); }                                 \
      holdB[i] = h; hnB_[i] = h;                                               \
    }                                                                          \
    f16x4 hvA = {(f16)hnA_[0],(f16)hnA_[1],(f16)hnA_[2],(f16)hnA_[3]};         \
    f16x4 hvB = {(f16)hnB_[0],(f16)hnB_[1],(f16)hnB_[2],(f16)hnB_[3]};         \
    *(f16x4*)(HWRA_) = hvA;                                                    \
    *(f16x4*)(HWRB_) = hvB;                                                    \
    if (!AUG) {                                                                \
      *(f16x4*)histpA = hvA;  histpA += H;                                     \
      *(f16x4*)histpB = hvB;  histpB += H;                                     \
    } else {                                                                   \
      if (t5_ == len_lA - 1) {                                                 \
        f32x4 ov = {hnA_[0],hnA_[1],hnA_[2],hnA_[3]};                          \
        *(f32x4*)outppA = ov;                                                  \
      }                                                                        \
      if (t5_ == len_lB - 1) {                                                 \
        f32x4 ov = {hnB_[0],hnB_[1],hnB_[2],hnB_[3]};                          \
        *(f32x4*)outppB = ov;                                                  \
      }                                                                        \
    }                                                                          \
    if (t5_ + 1 < T) {                                                         \
      if (AUG) {                                                               \
        *(f16x4*)(XSTA_) = PW16A;                                              \
        *(f16x4*)(XSTB_) = PW16B;                                              \
      } else {                                                                 \
        f16x4 sa_ = {(f16)PW32A.x,(f16)PW32A.y,(f16)PW32A.z,(f16)PW32A.w};     \
        f16x4 sb_ = {(f16)PW32B.x,(f16)PW32B.y,(f16)PW32B.z,(f16)PW32B.w};     \
        *(f16x4*)(XSTA_) = sa_;                                                \
        *(f16x4*)(XSTB_) = sb_;                                                \
      }                                                                        \
    }                                                                          \
    lds_sync();                                                                \
  }

  for (int t = 0; t < T; t += 2) {
    STEP(t,     xrdA0, hrdA0, hwrA1, xstA1, xrdB0, hrdB0, hwrB1, xstB1,
         Pa32A, Pb32A, Pa16A, Pb16A, AaA,
         Pa32B, Pb32B, Pa16B, Pb16B, AaB, pxEA32, pxEA16, pxEB32, pxEB16)
    STEP(t + 1, xrdA1, hrdA1, hwrA0, xstA0, xrdB1, hrdB1, hwrB0, xstB0,
         Pb32A, Pa32A, Pb16A, Pa16A, AbA,
         Pb32B, Pa32B, Pb16B, Pa16B, AbB, pxOA32, pxOA16, pxOB32, pxOB16)
  }
#undef STEP
}

// ---------------- DIN attention (MFMA version; rcp sigmoid — R10) ----------------
__global__ __launch_bounds__(256)
void attn_kernel(const float* __restrict__ query,
                 const f16*   __restrict__ hist,
                 const int*   __restrict__ mask,
                 const float* __restrict__ W1, const float* __restrict__ b1,
                 const float* __restrict__ W2, const float* __restrict__ b2,
                 float* __restrict__ attv, int T)
{
  __shared__ float qs[H];
  __shared__ f16   WqH[48 * PADW];
  __shared__ float qcp[48], w2p[48];
  __shared__ float logitsS[224];
  __shared__ float red[256];

  const int tid = threadIdx.x, b = blockIdx.x;
  const int w = tid >> 6, l = tid & 63, l16 = l & 15, lhi = l >> 4;

  if (tid < H) qs[tid] = query[b * H + tid];
  if (tid < 48) w2p[tid] = (tid < AH) ? W2[tid] : 0.f;
  __syncthreads();

  for (int i = tid; i < 48 * H; i += 256) {
    int u = i >> 7, k = i & (H - 1);
    float v = 0.f;
    if (u < AH) {
      const float* r = W1 + u * 4 * H;
      v = r[H + k] - r[2*H + k] + qs[k] * r[3*H + k];
    }
    WqH[u * PADW + k] = (f16)v;
  }
  if (tid < 48) {
    float s = 0.f;
    if (tid < AH) {
      const float* r = W1 + tid * 4 * H;
      s = b1[tid];
      for (int k = 0; k < H; ++k) s += qs[k] * (r[k] + r[2*H + k]);
    }
    qcp[tid] = s;
  }
  __syncthreads();

  const f32x4 qcv0 = *(const f32x4*)&qcp[lhi*4];
  const f32x4 qcv1 = *(const f32x4*)&qcp[16 + lhi*4];
  const f32x4 qcv2 = *(const f32x4*)&qcp[32 + lhi*4];
  const f32x4 w2v0 = *(const f32x4*)&w2p[lhi*4];
  const f32x4 w2v1 = *(const f32x4*)&w2p[16 + lhi*4];
  const f32x4 w2v2 = *(const f32x4*)&w2p[32 + lhi*4];

  const int NMT = (T + 15) >> 4;
  for (int mt = w; mt < NMT; mt += 4) {
    const int t0 = mt * 16;
    f16x8 hbf[4];
    #pragma unroll
    for (int q = 0; q < 4; ++q)
      hbf[q] = *(const f16x8*)(hist + ((size_t)b*T + t0 + l16)*H + q*32 + lhi*8);
    f32x4 d0 = {0,0,0,0}, d1 = {0,0,0,0}, d2 = {0,0,0,0};
    #pragma unroll
    for (int q = 0; q < 4; ++q) {
      f16x8 wq0 = *(const f16x8*)(&WqH[ l16       * PADW + q*32 + lhi*8]);
      f16x8 wq1 = *(const f16x8*)(&WqH[(16 + l16) * PADW + q*32 + lhi*8]);
      f16x8 wq2 = *(const f16x8*)(&WqH[(32 + l16) * PADW + q*32 + lhi*8]);
      d0 = __builtin_amdgcn_mfma_f32_16x16x32_f16(wq0, hbf[q], d0, 0,0,0);
      d1 = __builtin_amdgcn_mfma_f32_16x16x32_f16(wq1, hbf[q], d1, 0,0,0);
      d2 = __builtin_amdgcn_mfma_f32_16x16x32_f16(wq2, hbf[q], d2, 0,0,0);
    }
    float p = 0.f;
    #pragma unroll
    for (int i = 0; i < 4; ++i) {
      p += w2v0[i] * sigmoidf_(d0[i] + qcv0[i]);
      p += w2v1[i] * sigmoidf_(d1[i] + qcv1[i]);
      p += w2v2[i] * sigmoidf_(d2[i] + qcv2[i]);
    }
    p += __shfl_xor(p, 16, 64);
    p += __shfl_xor(p, 32, 64);
    if (lhi == 0) logitsS[t0 + l16] = p;
  }
  __syncthreads();

  const int t = tid;
  float logit = -1e30f; int mk = 0;
  if (t < T) {
    mk = mask[(size_t)b*T + t];
    logit = (mk > 0) ? (logitsS[t] + b2[0]) : -1e30f;
  }
  red[tid] = logit; __syncthreads();
  for (int s = 128; s > 0; s >>= 1) { if (tid < s) red[tid] = fmaxf(red[tid], red[tid+s]); __syncthreads(); }
  float mx = red[0]; __syncthreads();
  float ev = (t < T && mk > 0) ? __expf(logit - mx) : 0.f;
  red[tid] = ev; __syncthreads();
  for (int s = 128; s > 0; s >>= 1) { if (tid < s) red[tid] += red[tid+s]; __syncthreads(); }
  float sm = red[0];
  if (t < T) attv[(size_t)b*T + t] = ev * __builtin_amdgcn_rcpf(sm);
}

// ---------------- host ----------------
extern "C" void kernel_launch(void* const* d_in, const int* in_sizes, int n_in,
                              void* d_out, int out_size, void* d_ws, size_t ws_size,
                              hipStream_t stream)
{
  const float* query = (const float*)d_in[0];
  const float* ub    = (const float*)d_in[1];
  const int*   mask  = (const int*)d_in[2];
  const float* gWih  = (const float*)d_in[3];
  const float* gWhh  = (const float*)d_in[4];
  const float* gbih  = (const float*)d_in[5];
  const float* gbhh  = (const float*)d_in[6];
  const float* aW1   = (const float*)d_in[7];
  const float* ab1   = (const float*)d_in[8];
  const float* aW2   = (const float*)d_in[9];
  const float* ab2   = (const float*)d_in[10];
  const float* uWih  = (const float*)d_in[11];
  const float* uWhh  = (const float*)d_in[12];
  const float* ubih  = (const float*)d_in[13];
  const float* ubhh  = (const float*)d_in[14];

  const int B = in_sizes[0] / H;            // 1024
  const int T = in_sizes[1] / in_sizes[0];  // 200

  // workspace layout
  char*  ws   = (char*)d_ws;
  f16*   wf   = (f16*)ws;                                   // 393216 B
  int*   lenp = (int*)(ws + 393216);                        // 4096 B
  float* attb = (float*)(ws + 397312);                      // B*T*4
  f16*   hist = (f16*)(ws + 397312 + (size_t)B * 200 * 4);  // B*T*H f16

  prep_weights<<<(4 * G3 * H + 255) / 256, 256, 0, stream>>>(gWih, gWhh, uWih, uWhh, wf);
  prep_len<<<(B + 255) / 256, 256, 0, stream>>>(mask, lenp, T, B);

  scan_kernel<false><<<B / 32, 512, 0, stream>>>(
      ub, (const f16*)nullptr, wf, wf + G3 * H, gbih, gbhh,
      (const float*)nullptr, (const int*)nullptr, hist, (float*)nullptr, T);

  attn_kernel<<<B, 256, 0, stream>>>(query, hist, mask, aW1, ab1, aW2, ab2, attb, T);

  scan_kernel<true><<<B / 32, 512, 0, stream>>>(
      (const float*)nullptr, hist, wf + 2 * G3 * H, wf + 3 * G3 * H, ubih, ubhh,
      attb, lenp, (f16*)nullptr, (float*)d_out, T);
}

// Round 14
// 519.356 us; speedup vs baseline: 1.2573x; 1.2573x over previous
//
#include <hip/hip_runtime.h>

typedef _Float16 f16;
typedef _Float16 f16x8 __attribute__((ext_vector_type(8)));
typedef _Float16 f16x4 __attribute__((ext_vector_type(4)));
typedef float    f32x4 __attribute__((ext_vector_type(4)));

#define H  128
#define G3 384
#define AH 36
#define PADW 136   // padded LDS row: 136 f16 = 272B

// v_rcp_f32 (~1 ulp) — proven R10.
__device__ __forceinline__ float sigmoidf_(float x){
  return __builtin_amdgcn_rcpf(1.f + __expf(-x));
}
__device__ __forceinline__ float tanhf_(float x){
  return fmaf(2.f, __builtin_amdgcn_rcpf(1.f + __expf(-2.f*x)), -1.f);
}

// LDS-only barrier: global prefetch loads stay in flight across it.
__device__ __forceinline__ void lds_sync(){
  asm volatile("s_waitcnt lgkmcnt(0)" ::: "memory");
  __builtin_amdgcn_s_barrier();
  asm volatile("" ::: "memory");
}

// ---------------- prep: weights fp32 -> fp16, lengths, bulk convert ----------------
__global__ void prep_weights(const float* __restrict__ a, const float* __restrict__ b,
                             const float* __restrict__ c, const float* __restrict__ d,
                             f16* __restrict__ dst)
{
  int i = blockIdx.x * 256 + threadIdx.x;
  if (i >= 4 * G3 * H) return;
  int m = i / (G3 * H), j = i % (G3 * H);
  const float* s = (m == 0) ? a : (m == 1) ? b : (m == 2) ? c : d;
  dst[i] = (f16)s[j];
}

__global__ void prep_len(const int* __restrict__ mask, int* __restrict__ len, int T, int B)
{
  int b = blockIdx.x * 256 + threadIdx.x;
  if (b >= B) return;
  int s = 0;
  for (int t = 0; t < T; ++t) s += (mask[(size_t)b * T + t] > 0);
  len[b] = s;
}

// bulk f32 -> f16 convert (memory-bound, ~12us)
__global__ __launch_bounds__(256)
void prep_cvt(const float* __restrict__ src, f16* __restrict__ dst, int n8)
{
  int i = blockIdx.x * 256 + threadIdx.x;
  const int stride = gridDim.x * 256;
  for (; i < n8; i += stride) {
    f32x4 a = *(const f32x4*)(src + (size_t)i * 8);
    f32x4 b = *(const f32x4*)(src + (size_t)i * 8 + 4);
    f16x8 o = {(f16)a.x,(f16)a.y,(f16)a.z,(f16)a.w,(f16)b.x,(f16)b.y,(f16)b.z,(f16)b.w};
    *(f16x8*)(dst + (size_t)i * 8) = o;
  }
}

// ---------------- fused GRU / AUGRU scan (v11: R10 structure, x-frags from global) ----------------
// Identical MFMA interleave to R10. x B-frags live in registers, prefetched
// depth-2 from global (loads issued AFTER consumption -> one full step of
// latency cover, surviving across lds_sync). LDS holds only the h dbuf.
template<bool AUG>
__global__ __launch_bounds__(512)
__attribute__((amdgpu_waves_per_eu(2, 2)))
void scan_kernel(const f16*   __restrict__ xin,   // [B,T,H] f16 (ubf16 or hist)
                 const f16*   __restrict__ Wih,   // [3H][H] f16
                 const f16*   __restrict__ Whh,   // [3H][H] f16
                 const float* __restrict__ bih,
                 const float* __restrict__ bhh,
                 const float* __restrict__ att,   // [B,T] (AUG)
                 const int*   __restrict__ len,   // [B]   (AUG)
                 f16*         __restrict__ histo, // [B,T,H] f16 (GRU)
                 float*       __restrict__ outp,  // [B,H]       (AUG)
                 int T)
{
  __shared__ f16 hs[2][16 * PADW];

  const int tid = threadIdx.x;
  const int w   = tid >> 6;
  const int l   = tid & 63;
  const int l16 = l & 15;
  const int lhi = l >> 4;
  const int b0  = blockIdx.x * 16;
  const int colb = w * 16;
  const int c4   = colb + lhi * 4;
  const int srow = tid >> 5, cc = tid & 31;

  // Weight fragments (24 x f16x8 = 96 regs), pinned.
  f16x8 wih[3][4], whh[3][4];
  #pragma unroll
  for (int g = 0; g < 3; ++g)
    #pragma unroll
    for (int q = 0; q < 4; ++q) {
      int off = (g * H + colb + l16) * H + q * 32 + lhi * 8;
      wih[g][q] = *(const f16x8*)(Wih + off);
      whh[g][q] = *(const f16x8*)(Whh + off);
    }
  #pragma unroll
  for (int g = 0; g < 3; ++g)
    #pragma unroll
    for (int q = 0; q < 4; ++q)
      asm volatile("" : "+v"(wih[g][q]), "+v"(whh[g][q]));

  // bias C-inits
  f32x4 bRs = *(const f32x4*)(bih + c4);
  { f32x4 t2 = *(const f32x4*)(bhh + c4);     bRs += t2; }
  f32x4 bZs = *(const f32x4*)(bih + H + c4);
  { f32x4 t2 = *(const f32x4*)(bhh + H + c4); bZs += t2; }
  f32x4 bXn = *(const f32x4*)(bih + 2*H + c4);
  f32x4 bHn = *(const f32x4*)(bhh + 2*H + c4);

  float hold[4] = {0.f, 0.f, 0.f, 0.f};
  int len_l = 0;
  if (AUG) len_l = len[b0 + l16];

  // LDS pointers (h double buffer only)
  const f16* hrd0 = &hs[0][l16 * PADW + lhi * 8];   // + q*32 at use
  const f16* hrd1 = &hs[1][l16 * PADW + lhi * 8];
  f16* hwr0 = &hs[0][l16 * PADW + c4];
  f16* hwr1 = &hs[1][l16 * PADW + c4];

  // global pointers (per-lane x-fragment base: row = b0+l16, + lhi*8)
  const f16* pxBase = xin + ((size_t)(b0 + l16) * T) * H + lhi * 8;
  const float* attB = AUG ? (att + (size_t)(b0 + l16) * T) : nullptr;
  f16*   histp = (!AUG && histo) ? (histo + ((size_t)(b0 + l16) * T) * H + c4) : nullptr;
  float* outpp = AUG ? (outp + (size_t)(b0 + l16) * H + c4) : nullptr;

  // prologue: zero h buf0; x frags for t=0 (xbA) and t=1 (xbB); att scalars
  {
    f16x4 z4 = {(f16)0, (f16)0, (f16)0, (f16)0};
    *(f16x4*)(&hs[0][srow * PADW + cc * 4]) = z4;
  }
  f16x8 xbA[4], xbB[4];
  #pragma unroll
  for (int q = 0; q < 4; ++q) xbA[q] = *(const f16x8*)(pxBase + q * 32);
  if (T > 1)
    #pragma unroll
    for (int q = 0; q < 4; ++q) xbB[q] = *(const f16x8*)(pxBase + H + q * 32);
  const f16* pxE = pxBase + 2 * H;   // reload target for even steps (t+2)
  const f16* pxO = pxBase + 3 * H;   // reload target for odd steps  (t+2)
  float Aa = 0.f, Ab = 0.f;
  if (AUG) {
    Aa = attB[0];
    if (T > 1) Ab = attB[1];
  }
  lds_sync();

// XBW: frag array consumed this step, reloaded (t+2) after consumption.
// Macro-internal names suffixed (R3 lesson). MFMA interleave identical to R10.
#define STEP(targ_, XBW, HRD, HWRN, AW, PXP)                                   \
  {                                                                            \
    const int t5_ = (targ_);                                                   \
    float at_ = 0.f;                                                           \
    if (AUG) at_ = AW;                                                         \
    f16x8 hb[4];                                                               \
    _Pragma("unroll")                                                          \
    for (int q = 0; q < 4; ++q) hb[q] = *(const f16x8*)(HRD + q * 32);         \
    f32x4 aR = bRs, aZ = bZs, aXn = bXn, aHn = bHn;                            \
    _Pragma("unroll")                                                          \
    for (int q = 0; q < 4; ++q) {                                              \
      aR  = __builtin_amdgcn_mfma_f32_16x16x32_f16(wih[0][q], XBW[q], aR, 0,0,0); \
      aZ  = __builtin_amdgcn_mfma_f32_16x16x32_f16(wih[1][q], XBW[q], aZ, 0,0,0); \
      aXn = __builtin_amdgcn_mfma_f32_16x16x32_f16(wih[2][q], XBW[q], aXn,0,0,0); \
      aHn = __builtin_amdgcn_mfma_f32_16x16x32_f16(whh[2][q], hb[q],  aHn,0,0,0); \
    }                                                                          \
    _Pragma("unroll")                                                          \
    for (int q = 0; q < 4; ++q) {                                              \
      aR  = __builtin_amdgcn_mfma_f32_16x16x32_f16(whh[0][q], hb[q], aR, 0,0,0);  \
      aZ  = __builtin_amdgcn_mfma_f32_16x16x32_f16(whh[1][q], hb[q], aZ, 0,0,0);  \
    }                                                                          \
    float hn_[4];                                                              \
    _Pragma("unroll")                                                          \
    for (int i = 0; i < 4; ++i) {                                              \
      float r = sigmoidf_(aR[i]);                                              \
      float z = sigmoidf_(aZ[i]);                                              \
      float n = tanhf_(aXn[i] + r * aHn[i]);                                   \
      float h;                                                                 \
      if (AUG) { float u = z * at_; h = hold[i] + u * (n - hold[i]); }         \
      else     { h = n + z * (hold[i] - n); }                                  \
      hold[i] = h; hn_[i] = h;                                                 \
    }                                                                          \
    f16x4 hv = {(f16)hn_[0], (f16)hn_[1], (f16)hn_[2], (f16)hn_[3]};           \
    *(f16x4*)(HWRN) = hv;                                                      \
    if (!AUG) {                                                                \
      *(f16x4*)histp = hv;  histp += H;                                        \
    } else {                                                                   \
      if (t5_ == len_l - 1) {                                                  \
        f32x4 ov = {hn_[0], hn_[1], hn_[2], hn_[3]};                           \
        *(f32x4*)outpp = ov;                                                   \
      }                                                                        \
    }                                                                          \
    /* reload this parity's frags for t+2 (consumed two steps later; */        \
    /* ~1 full step of latency cover, stays in flight across lds_sync) */      \
    if (t5_ + 2 < T) {                                                         \
      _Pragma("unroll")                                                        \
      for (int q = 0; q < 4; ++q) XBW[q] = *(const f16x8*)(PXP + q * 32);      \
      PXP += 2 * H;                                                            \
      if (AUG) AW = attB[t5_ + 2];                                             \
    }                                                                          \
    lds_sync();                                                                \
  }

  for (int t = 0; t < T; t += 2) {
    STEP(t,     xbA, hrd0, hwr1, Aa, pxE)
    STEP(t + 1, xbB, hrd1, hwr0, Ab, pxO)
  }
#undef STEP
}

// ---------------- DIN attention (MFMA version; rcp sigmoid — R10) ----------------
__global__ __launch_bounds__(256)
void attn_kernel(const float* __restrict__ query,
                 const f16*   __restrict__ hist,
                 const int*   __restrict__ mask,
                 const float* __restrict__ W1, const float* __restrict__ b1,
                 const float* __restrict__ W2, const float* __restrict__ b2,
                 float* __restrict__ attv, int T)
{
  __shared__ float qs[H];
  __shared__ f16   WqH[48 * PADW];
  __shared__ float qcp[48], w2p[48];
  __shared__ float logitsS[224];
  __shared__ float red[256];

  const int tid = threadIdx.x, b = blockIdx.x;
  const int w = tid >> 6, l = tid & 63, l16 = l & 15, lhi = l >> 4;

  if (tid < H) qs[tid] = query[b * H + tid];
  if (tid < 48) w2p[tid] = (tid < AH) ? W2[tid] : 0.f;
  __syncthreads();

  for (int i = tid; i < 48 * H; i += 256) {
    int u = i >> 7, k = i & (H - 1);
    float v = 0.f;
    if (u < AH) {
      const float* r = W1 + u * 4 * H;
      v = r[H + k] - r[2*H + k] + qs[k] * r[3*H + k];
    }
    WqH[u * PADW + k] = (f16)v;
  }
  if (tid < 48) {
    float s = 0.f;
    if (tid < AH) {
      const float* r = W1 + tid * 4 * H;
      s = b1[tid];
      for (int k = 0; k < H; ++k) s += qs[k] * (r[k] + r[2*H + k]);
    }
    qcp[tid] = s;
  }
  __syncthreads();

  const f32x4 qcv0 = *(const f32x4*)&qcp[lhi*4];
  const f32x4 qcv1 = *(const f32x4*)&qcp[16 + lhi*4];
  const f32x4 qcv2 = *(const f32x4*)&qcp[32 + lhi*4];
  const f32x4 w2v0 = *(const f32x4*)&w2p[lhi*4];
  const f32x4 w2v1 = *(const f32x4*)&w2p[16 + lhi*4];
  const f32x4 w2v2 = *(const f32x4*)&w2p[32 + lhi*4];

  const int NMT = (T + 15) >> 4;
  for (int mt = w; mt < NMT; mt += 4) {
    const int t0 = mt * 16;
    f16x8 hbf[4];
    #pragma unroll
    for (int q = 0; q < 4; ++q)
      hbf[q] = *(const f16x8*)(hist + ((size_t)b*T + t0 + l16)*H + q*32 + lhi*8);
    f32x4 d0 = {0,0,0,0}, d1 = {0,0,0,0}, d2 = {0,0,0,0};
    #pragma unroll
    for (int q = 0; q < 4; ++q) {
      f16x8 wq0 = *(const f16x8*)(&WqH[ l16       * PADW + q*32 + lhi*8]);
      f16x8 wq1 = *(const f16x8*)(&WqH[(16 + l16) * PADW + q*32 + lhi*8]);
      f16x8 wq2 = *(const f16x8*)(&WqH[(32 + l16) * PADW + q*32 + lhi*8]);
      d0 = __builtin_amdgcn_mfma_f32_16x16x32_f16(wq0, hbf[q], d0, 0,0,0);
      d1 = __builtin_amdgcn_mfma_f32_16x16x32_f16(wq1, hbf[q], d1, 0,0,0);
      d2 = __builtin_amdgcn_mfma_f32_16x16x32_f16(wq2, hbf[q], d2, 0,0,0);
    }
    float p = 0.f;
    #pragma unroll
    for (int i = 0; i < 4; ++i) {
      p += w2v0[i] * sigmoidf_(d0[i] + qcv0[i]);
      p += w2v1[i] * sigmoidf_(d1[i] + qcv1[i]);
      p += w2v2[i] * sigmoidf_(d2[i] + qcv2[i]);
    }
    p += __shfl_xor(p, 16, 64);
    p += __shfl_xor(p, 32, 64);
    if (lhi == 0) logitsS[t0 + l16] = p;
  }
  __syncthreads();

  const int t = tid;
  float logit = -1e30f; int mk = 0;
  if (t < T) {
    mk = mask[(size_t)b*T + t];
    logit = (mk > 0) ? (logitsS[t] + b2[0]) : -1e30f;
  }
  red[tid] = logit; __syncthreads();
  for (int s = 128; s > 0; s >>= 1) { if (tid < s) red[tid] = fmaxf(red[tid], red[tid+s]); __syncthreads(); }
  float mx = red[0]; __syncthreads();
  float ev = (t < T && mk > 0) ? __expf(logit - mx) : 0.f;
  red[tid] = ev; __syncthreads();
  for (int s = 128; s > 0; s >>= 1) { if (tid < s) red[tid] += red[tid+s]; __syncthreads(); }
  float sm = red[0];
  if (t < T) attv[(size_t)b*T + t] = ev * __builtin_amdgcn_rcpf(sm);
}

// ---------------- host ----------------
extern "C" void kernel_launch(void* const* d_in, const int* in_sizes, int n_in,
                              void* d_out, int out_size, void* d_ws, size_t ws_size,
                              hipStream_t stream)
{
  const float* query = (const float*)d_in[0];
  const float* ub    = (const float*)d_in[1];
  const int*   mask  = (const int*)d_in[2];
  const float* gWih  = (const float*)d_in[3];
  const float* gWhh  = (const float*)d_in[4];
  const float* gbih  = (const float*)d_in[5];
  const float* gbhh  = (const float*)d_in[6];
  const float* aW1   = (const float*)d_in[7];
  const float* ab1   = (const float*)d_in[8];
  const float* aW2   = (const float*)d_in[9];
  const float* ab2   = (const float*)d_in[10];
  const float* uWih  = (const float*)d_in[11];
  const float* uWhh  = (const float*)d_in[12];
  const float* ubih  = (const float*)d_in[13];
  const float* ubhh  = (const float*)d_in[14];

  const int B = in_sizes[0] / H;            // 1024
  const int T = in_sizes[1] / in_sizes[0];  // 200

  // workspace layout
  char*  ws    = (char*)d_ws;
  f16*   wf    = (f16*)ws;                                  // 393216 B
  int*   lenp  = (int*)(ws + 393216);                       // 4096 B
  float* attb  = (float*)(ws + 397312);                     // B*T*4 = 819200
  f16*   hist  = (f16*)(ws + 1216512);                      // B*T*H*2 = 52428800
  f16*   ubf16 = (f16*)(ws + 1216512 + 52428800);           // B*T*H*2 = 52428800

  prep_weights<<<(4 * G3 * H + 255) / 256, 256, 0, stream>>>(gWih, gWhh, uWih, uWhh, wf);
  prep_len<<<(B + 255) / 256, 256, 0, stream>>>(mask, lenp, T, B);
  prep_cvt<<<2048, 256, 0, stream>>>(ub, ubf16, B * T * H / 8);

  scan_kernel<false><<<B / 16, 512, 0, stream>>>(
      ubf16, wf, wf + G3 * H, gbih, gbhh,
      (const float*)nullptr, (const int*)nullptr, hist, (float*)nullptr, T);

  attn_kernel<<<B, 256, 0, stream>>>(query, hist, mask, aW1, ab1, aW2, ab2, attb, T);

  scan_kernel<true><<<B / 16, 512, 0, stream>>>(
      hist, wf + 2 * G3 * H, wf + 3 * G3 * H, ubih, ubhh,
      attb, lenp, (f16*)nullptr, (float*)d_out, T);
}

// Round 15
// 443.639 us; speedup vs baseline: 1.4719x; 1.1707x over previous
//
#include <hip/hip_runtime.h>

typedef _Float16 f16;
typedef _Float16 f16x8 __attribute__((ext_vector_type(8)));
typedef _Float16 f16x4 __attribute__((ext_vector_type(4)));
typedef float    f32x4 __attribute__((ext_vector_type(4)));

#define H    128
#define G3   384
#define AH   36
#define PADW 136          // f16 row pad (272B)
#define XAP  20           // xa row pad (f32, 80B)
#define XTS  (16 * XAP)   // xa tile stride (floats)

__device__ __forceinline__ float sigmoidf_(float x){
  return __builtin_amdgcn_rcpf(1.f + __expf(-x));
}
__device__ __forceinline__ float tanhf_(float x){
  return fmaf(2.f, __builtin_amdgcn_rcpf(1.f + __expf(-2.f*x)), -1.f);
}
// LDS-only barrier: global prefetch loads stay in flight across it.
__device__ __forceinline__ void lds_sync(){
  asm volatile("s_waitcnt lgkmcnt(0)" ::: "memory");
  __builtin_amdgcn_s_barrier();
  asm volatile("" ::: "memory");
}

// ---------------- prep ----------------
__global__ void prep_weights(const float* __restrict__ a, const float* __restrict__ b,
                             const float* __restrict__ c, const float* __restrict__ d,
                             f16* __restrict__ dst)
{
  int i = blockIdx.x * 256 + threadIdx.x;
  if (i >= 4 * G3 * H) return;
  int m = i / (G3 * H), j = i % (G3 * H);
  const float* s = (m == 0) ? a : (m == 1) ? b : (m == 2) ? c : d;
  dst[i] = (f16)s[j];
}

__global__ void prep_len(const int* __restrict__ mask, int* __restrict__ len, int T, int B)
{
  int b = blockIdx.x * 256 + threadIdx.x;
  if (b >= B) return;
  int s = 0;
  for (int t = 0; t < T; ++t) s += (mask[(size_t)b * T + t] > 0);
  len[b] = s;
}

__global__ __launch_bounds__(256)
void prep_cvt(const float* __restrict__ src, f16* __restrict__ dst, int n8)
{
  int i = blockIdx.x * 256 + threadIdx.x;
  const int stride = gridDim.x * 256;
  for (; i < n8; i += stride) {
    f32x4 a = *(const f32x4*)(src + (size_t)i * 8);
    f32x4 b = *(const f32x4*)(src + (size_t)i * 8 + 4);
    f16x8 o = {(f16)a.x,(f16)a.y,(f16)a.z,(f16)a.w,(f16)b.x,(f16)b.y,(f16)b.z,(f16)b.w};
    *(f16x8*)(dst + (size_t)i * 8) = o;
  }
}

// ---------------- wave-specialized scan (v12) ----------------
// Block = 16 batch rows, 8 waves. Waves 0-3 ("H role", col group 32w) do the
// h-GEMM + gates for step t; waves 4-7 ("X role", same col groups) do the
// x-GEMM for step t+1 into LDS xacc (f32, bias folded). Separate weight
// register files per role -> true cross-wave phase overlap. Two barriers/step:
// reads (xs/hs/xa) pre-B, writes post-B -> all LDS single-buffered.
template<bool AUG>
__global__ __launch_bounds__(512)
__attribute__((amdgpu_waves_per_eu(2, 2)))
void scan_kernel(const f16*   __restrict__ xin,   // [B,T,H] f16 (ubf16 or hist)
                 const f16*   __restrict__ Wih,
                 const f16*   __restrict__ Whh,
                 const float* __restrict__ bih,
                 const float* __restrict__ bhh,
                 const float* __restrict__ att,   // [B,T] (AUG)
                 const int*   __restrict__ len,   // [B]   (AUG)
                 f16*         __restrict__ histo, // [B,T,H] f16 (GRU)
                 float*       __restrict__ outp,  // [B,H]       (AUG)
                 int T)
{
  __shared__ f16   xsS[16 * PADW];          // x_{t+1} staging
  __shared__ f16   hsS[16 * PADW];          // h_t
  __shared__ float xaS[4 * 6 * XTS];        // xacc: [wavegrp][g*2+c][16 rows][XAP]

  const int tid = threadIdx.x;
  const int w   = tid >> 6;
  const int l   = tid & 63;
  const int l16 = l & 15;
  const int lhi = l >> 4;
  const int b0  = blockIdx.x * 16;
  const int wq  = w & 3;
  const int cb  = wq * 32;          // this role-pair owns h cols [cb, cb+32)
  const int c40 = cb + lhi * 4;

  // zero h (all threads)
  { f16x4 z4 = {(f16)0,(f16)0,(f16)0,(f16)0};
    *(f16x4*)(&hsS[(tid >> 5) * PADW + (tid & 31) * 4]) = z4; }

  float* const xa00 = &xaS[wq * 6 * XTS + (size_t)l16 * XAP + lhi * 4];

  if (w < 4) {
    // ================= H role =================
    f16x8 whhF[3][2][4];
    #pragma unroll
    for (int g = 0; g < 3; ++g)
      #pragma unroll
      for (int c = 0; c < 2; ++c)
        #pragma unroll
        for (int q = 0; q < 4; ++q)
          whhF[g][c][q] = *(const f16x8*)(Whh + (size_t)(g*H + cb + 16*c + l16)*H + q*32 + lhi*8);
    #pragma unroll
    for (int g = 0; g < 3; ++g)
      #pragma unroll
      for (int c = 0; c < 2; ++c)
        #pragma unroll
        for (int q = 0; q < 4; ++q)
          asm volatile("" : "+v"(whhF[g][c][q]));

    const f32x4 bHn0 = *(const f32x4*)(bhh + 2*H + c40);
    const f32x4 bHn1 = *(const f32x4*)(bhh + 2*H + c40 + 16);

    float hold0[4] = {0.f,0.f,0.f,0.f}, hold1[4] = {0.f,0.f,0.f,0.f};
    int len_l = 0;
    if (AUG) len_l = len[b0 + l16];
    const float* attB = AUG ? (att + (size_t)(b0 + l16) * T) : nullptr;
    f16*   histp = (!AUG && histo) ? (histo + ((size_t)(b0 + l16) * T) * H + c40) : nullptr;
    float* outpp = AUG ? (outp + (size_t)(b0 + l16) * H + c40) : nullptr;

    const f16* hrdH = &hsS[l16 * PADW + lhi * 8];
    f16*       hwrH = &hsS[l16 * PADW + c40];

    lds_sync();                                  // prologue barrier

    for (int t = 0; t < T; ++t) {
      float at_ = 0.f;
      if (AUG) at_ = attB[t];
      f16x8 hbq[4];
      #pragma unroll
      for (int q = 0; q < 4; ++q) hbq[q] = *(const f16x8*)(hrdH + q * 32);
      const f32x4 xr0 = *(const f32x4*)(xa00 + 0 * XTS);
      const f32x4 xr1 = *(const f32x4*)(xa00 + 1 * XTS);
      const f32x4 xz0 = *(const f32x4*)(xa00 + 2 * XTS);
      const f32x4 xz1 = *(const f32x4*)(xa00 + 3 * XTS);
      const f32x4 xn0 = *(const f32x4*)(xa00 + 4 * XTS);
      const f32x4 xn1 = *(const f32x4*)(xa00 + 5 * XTS);
      f32x4 a00={0,0,0,0}, a01={0,0,0,0}, a10={0,0,0,0}, a11={0,0,0,0};
      f32x4 a20 = bHn0, a21 = bHn1;
      #pragma unroll
      for (int q = 0; q < 4; ++q) {
        a00 = __builtin_amdgcn_mfma_f32_16x16x32_f16(whhF[0][0][q], hbq[q], a00, 0,0,0);
        a01 = __builtin_amdgcn_mfma_f32_16x16x32_f16(whhF[0][1][q], hbq[q], a01, 0,0,0);
        a10 = __builtin_amdgcn_mfma_f32_16x16x32_f16(whhF[1][0][q], hbq[q], a10, 0,0,0);
        a11 = __builtin_amdgcn_mfma_f32_16x16x32_f16(whhF[1][1][q], hbq[q], a11, 0,0,0);
        a20 = __builtin_amdgcn_mfma_f32_16x16x32_f16(whhF[2][0][q], hbq[q], a20, 0,0,0);
        a21 = __builtin_amdgcn_mfma_f32_16x16x32_f16(whhF[2][1][q], hbq[q], a21, 0,0,0);
      }
      lds_sync();                                // barrier B (reads done)
      float hn0[4], hn1[4];
      #pragma unroll
      for (int i = 0; i < 4; ++i) {
        float r = sigmoidf_(xr0[i] + a00[i]);
        float z = sigmoidf_(xz0[i] + a10[i]);
        float n = tanhf_(xn0[i] + r * a20[i]);
        float h;
        if (AUG) { float u = z * at_; h = hold0[i] + u * (n - hold0[i]); }
        else     { h = n + z * (hold0[i] - n); }
        hold0[i] = h; hn0[i] = h;
      }
      #pragma unroll
      for (int i = 0; i < 4; ++i) {
        float r = sigmoidf_(xr1[i] + a01[i]);
        float z = sigmoidf_(xz1[i] + a11[i]);
        float n = tanhf_(xn1[i] + r * a21[i]);
        float h;
        if (AUG) { float u = z * at_; h = hold1[i] + u * (n - hold1[i]); }
        else     { h = n + z * (hold1[i] - n); }
        hold1[i] = h; hn1[i] = h;
      }
      f16x4 hv0 = {(f16)hn0[0],(f16)hn0[1],(f16)hn0[2],(f16)hn0[3]};
      f16x4 hv1 = {(f16)hn1[0],(f16)hn1[1],(f16)hn1[2],(f16)hn1[3]};
      *(f16x4*)(hwrH)      = hv0;
      *(f16x4*)(hwrH + 16) = hv1;
      if (!AUG) {
        *(f16x4*)(histp)      = hv0;
        *(f16x4*)(histp + 16) = hv1;
        histp += H;
      } else if (t == len_l - 1) {
        f32x4 o0 = {hn0[0],hn0[1],hn0[2],hn0[3]};
        f32x4 o1 = {hn1[0],hn1[1],hn1[2],hn1[3]};
        *(f32x4*)(outpp)      = o0;
        *(f32x4*)(outpp + 16) = o1;
      }
      lds_sync();                                // barrier A (step end)
    }
  } else {
    // ================= X role =================
    f16x8 wihF[3][2][4];
    #pragma unroll
    for (int g = 0; g < 3; ++g)
      #pragma unroll
      for (int c = 0; c < 2; ++c)
        #pragma unroll
        for (int q = 0; q < 4; ++q)
          wihF[g][c][q] = *(const f16x8*)(Wih + (size_t)(g*H + cb + 16*c + l16)*H + q*32 + lhi*8);
    #pragma unroll
    for (int g = 0; g < 3; ++g)
      #pragma unroll
      for (int c = 0; c < 2; ++c)
        #pragma unroll
        for (int q = 0; q < 4; ++q)
          asm volatile("" : "+v"(wihF[g][c][q]));

    f32x4 bR0 = *(const f32x4*)(bih + c40);
    { f32x4 t2 = *(const f32x4*)(bhh + c40);          bR0 += t2; }
    f32x4 bR1 = *(const f32x4*)(bih + c40 + 16);
    { f32x4 t2 = *(const f32x4*)(bhh + c40 + 16);     bR1 += t2; }
    f32x4 bZ0 = *(const f32x4*)(bih + H + c40);
    { f32x4 t2 = *(const f32x4*)(bhh + H + c40);      bZ0 += t2; }
    f32x4 bZ1 = *(const f32x4*)(bih + H + c40 + 16);
    { f32x4 t2 = *(const f32x4*)(bhh + H + c40 + 16); bZ1 += t2; }
    const f32x4 bN0 = *(const f32x4*)(bih + 2*H + c40);
    const f32x4 bN1 = *(const f32x4*)(bih + 2*H + c40 + 16);

    const int j    = tid & 255;
    const int srow = j >> 4, scol = (j & 15) * 8;
    const f16* pxStage = xin + ((size_t)(b0 + srow) * T) * H + scol;  // + t*H
    const f16* xrdX    = &xsS[l16 * PADW + lhi * 8];

    // prologue: xacc_0 from x_0 (per-lane global frags, one-time)
    {
      const f16* pxF0 = xin + ((size_t)(b0 + l16) * T) * H + lhi * 8;
      f16x8 xb0[4];
      #pragma unroll
      for (int q = 0; q < 4; ++q) xb0[q] = *(const f16x8*)(pxF0 + q * 32);
      f32x4 c00=bR0, c01=bR1, c10=bZ0, c11=bZ1, c20=bN0, c21=bN1;
      #pragma unroll
      for (int q = 0; q < 4; ++q) {
        c00 = __builtin_amdgcn_mfma_f32_16x16x32_f16(wihF[0][0][q], xb0[q], c00, 0,0,0);
        c01 = __builtin_amdgcn_mfma_f32_16x16x32_f16(wihF[0][1][q], xb0[q], c01, 0,0,0);
        c10 = __builtin_amdgcn_mfma_f32_16x16x32_f16(wihF[1][0][q], xb0[q], c10, 0,0,0);
        c11 = __builtin_amdgcn_mfma_f32_16x16x32_f16(wihF[1][1][q], xb0[q], c11, 0,0,0);
        c20 = __builtin_amdgcn_mfma_f32_16x16x32_f16(wihF[2][0][q], xb0[q], c20, 0,0,0);
        c21 = __builtin_amdgcn_mfma_f32_16x16x32_f16(wihF[2][1][q], xb0[q], c21, 0,0,0);
      }
      *(f32x4*)(xa00 + 0 * XTS) = c00;
      *(f32x4*)(xa00 + 1 * XTS) = c01;
      *(f32x4*)(xa00 + 2 * XTS) = c10;
      *(f32x4*)(xa00 + 3 * XTS) = c11;
      *(f32x4*)(xa00 + 4 * XTS) = c20;
      *(f32x4*)(xa00 + 5 * XTS) = c21;
    }
    // stage x_1, prefetch x_2 / x_3
    if (T > 1) *(f16x8*)(&xsS[srow * PADW + scol]) = *(const f16x8*)(pxStage + H);
    f16x8 PWa = {}, PWb = {};
    if (T > 2) PWa = *(const f16x8*)(pxStage + 2 * H);
    if (T > 3) PWb = *(const f16x8*)(pxStage + 3 * H);
    const f16* pxSa = pxStage + 4 * H;
    const f16* pxSb = pxStage + 5 * H;

    lds_sync();                                  // prologue barrier

#define XBODY(t5v, PW, PXS)                                                    \
    {                                                                          \
      const int t5_ = (t5v);                                                   \
      if (t5_ < T) {                                                           \
        f16x8 xbq[4];                                                          \
        _Pragma("unroll")                                                      \
        for (int q = 0; q < 4; ++q) xbq[q] = *(const f16x8*)(xrdX + q * 32);   \
        f32x4 c00=bR0, c01=bR1, c10=bZ0, c11=bZ1, c20=bN0, c21=bN1;            \
        _Pragma("unroll")                                                      \
        for (int q = 0; q < 4; ++q) {                                          \
          c00 = __builtin_amdgcn_mfma_f32_16x16x32_f16(wihF[0][0][q], xbq[q], c00, 0,0,0); \
          c01 = __builtin_amdgcn_mfma_f32_16x16x32_f16(wihF[0][1][q], xbq[q], c01, 0,0,0); \
          c10 = __builtin_amdgcn_mfma_f32_16x16x32_f16(wihF[1][0][q], xbq[q], c10, 0,0,0); \
          c11 = __builtin_amdgcn_mfma_f32_16x16x32_f16(wihF[1][1][q], xbq[q], c11, 0,0,0); \
          c20 = __builtin_amdgcn_mfma_f32_16x16x32_f16(wihF[2][0][q], xbq[q], c20, 0,0,0); \
          c21 = __builtin_amdgcn_mfma_f32_16x16x32_f16(wihF[2][1][q], xbq[q], c21, 0,0,0); \
        }                                                                      \
        lds_sync();  /* barrier B */                                           \
        *(f32x4*)(xa00 + 0 * XTS) = c00;                                       \
        *(f32x4*)(xa00 + 1 * XTS) = c01;                                       \
        *(f32x4*)(xa00 + 2 * XTS) = c10;                                       \
        *(f32x4*)(xa00 + 3 * XTS) = c11;                                       \
        *(f32x4*)(xa00 + 4 * XTS) = c20;                                       \
        *(f32x4*)(xa00 + 5 * XTS) = c21;                                       \
        if (t5_ + 2 < T) *(f16x8*)(&xsS[srow * PADW + scol]) = PW;             \
        if (t5_ + 4 < T) { PW = *(const f16x8*)(PXS); PXS += 2 * H; }          \
        lds_sync();  /* barrier A */                                           \
      }                                                                        \
    }

    for (int t = 0; t < T; t += 2) {
      XBODY(t,     PWa, pxSa)
      XBODY(t + 1, PWb, pxSb)
    }
#undef XBODY
  }
}

// ---------------- DIN attention (MFMA version; rcp sigmoid — R10) ----------------
__global__ __launch_bounds__(256)
void attn_kernel(const float* __restrict__ query,
                 const f16*   __restrict__ hist,
                 const int*   __restrict__ mask,
                 const float* __restrict__ W1, const float* __restrict__ b1,
                 const float* __restrict__ W2, const float* __restrict__ b2,
                 float* __restrict__ attv, int T)
{
  __shared__ float qs[H];
  __shared__ f16   WqH[48 * PADW];
  __shared__ float qcp[48], w2p[48];
  __shared__ float logitsS[224];
  __shared__ float red[256];

  const int tid = threadIdx.x, b = blockIdx.x;
  const int w = tid >> 6, l = tid & 63, l16 = l & 15, lhi = l >> 4;

  if (tid < H) qs[tid] = query[b * H + tid];
  if (tid < 48) w2p[tid] = (tid < AH) ? W2[tid] : 0.f;
  __syncthreads();

  for (int i = tid; i < 48 * H; i += 256) {
    int u = i >> 7, k = i & (H - 1);
    float v = 0.f;
    if (u < AH) {
      const float* r = W1 + u * 4 * H;
      v = r[H + k] - r[2*H + k] + qs[k] * r[3*H + k];
    }
    WqH[u * PADW + k] = (f16)v;
  }
  if (tid < 48) {
    float s = 0.f;
    if (tid < AH) {
      const float* r = W1 + tid * 4 * H;
      s = b1[tid];
      for (int k = 0; k < H; ++k) s += qs[k] * (r[k] + r[2*H + k]);
    }
    qcp[tid] = s;
  }
  __syncthreads();

  const f32x4 qcv0 = *(const f32x4*)&qcp[lhi*4];
  const f32x4 qcv1 = *(const f32x4*)&qcp[16 + lhi*4];
  const f32x4 qcv2 = *(const f32x4*)&qcp[32 + lhi*4];
  const f32x4 w2v0 = *(const f32x4*)&w2p[lhi*4];
  const f32x4 w2v1 = *(const f32x4*)&w2p[16 + lhi*4];
  const f32x4 w2v2 = *(const f32x4*)&w2p[32 + lhi*4];

  const int NMT = (T + 15) >> 4;
  for (int mt = w; mt < NMT; mt += 4) {
    const int t0 = mt * 16;
    f16x8 hbf[4];
    #pragma unroll
    for (int q = 0; q < 4; ++q)
      hbf[q] = *(const f16x8*)(hist + ((size_t)b*T + t0 + l16)*H + q*32 + lhi*8);
    f32x4 d0 = {0,0,0,0}, d1 = {0,0,0,0}, d2 = {0,0,0,0};
    #pragma unroll
    for (int q = 0; q < 4; ++q) {
      f16x8 wq0 = *(const f16x8*)(&WqH[ l16       * PADW + q*32 + lhi*8]);
      f16x8 wq1 = *(const f16x8*)(&WqH[(16 + l16) * PADW + q*32 + lhi*8]);
      f16x8 wq2 = *(const f16x8*)(&WqH[(32 + l16) * PADW + q*32 + lhi*8]);
      d0 = __builtin_amdgcn_mfma_f32_16x16x32_f16(wq0, hbf[q], d0, 0,0,0);
      d1 = __builtin_amdgcn_mfma_f32_16x16x32_f16(wq1, hbf[q], d1, 0,0,0);
      d2 = __builtin_amdgcn_mfma_f32_16x16x32_f16(wq2, hbf[q], d2, 0,0,0);
    }
    float p = 0.f;
    #pragma unroll
    for (int i = 0; i < 4; ++i) {
      p += w2v0[i] * sigmoidf_(d0[i] + qcv0[i]);
      p += w2v1[i] * sigmoidf_(d1[i] + qcv1[i]);
      p += w2v2[i] * sigmoidf_(d2[i] + qcv2[i]);
    }
    p += __shfl_xor(p, 16, 64);
    p += __shfl_xor(p, 32, 64);
    if (lhi == 0) logitsS[t0 + l16] = p;
  }
  __syncthreads();

  const int t = tid;
  float logit = -1e30f; int mk = 0;
  if (t < T) {
    mk = mask[(size_t)b*T + t];
    logit = (mk > 0) ? (logitsS[t] + b2[0]) : -1e30f;
  }
  red[tid] = logit; __syncthreads();
  for (int s = 128; s > 0; s >>= 1) { if (tid < s) red[tid] = fmaxf(red[tid], red[tid+s]); __syncthreads(); }
  float mx = red[0]; __syncthreads();
  float ev = (t < T && mk > 0) ? __expf(logit - mx) : 0.f;
  red[tid] = ev; __syncthreads();
  for (int s = 128; s > 0; s >>= 1) { if (tid < s) red[tid] += red[tid+s]; __syncthreads(); }
  float sm = red[0];
  if (t < T) attv[(size_t)b*T + t] = ev * __builtin_amdgcn_rcpf(sm);
}

// ---------------- host ----------------
extern "C" void kernel_launch(void* const* d_in, const int* in_sizes, int n_in,
                              void* d_out, int out_size, void* d_ws, size_t ws_size,
                              hipStream_t stream)
{
  const float* query = (const float*)d_in[0];
  const float* ub    = (const float*)d_in[1];
  const int*   mask  = (const int*)d_in[2];
  const float* gWih  = (const float*)d_in[3];
  const float* gWhh  = (const float*)d_in[4];
  const float* gbih  = (const float*)d_in[5];
  const float* gbhh  = (const float*)d_in[6];
  const float* aW1   = (const float*)d_in[7];
  const float* ab1   = (const float*)d_in[8];
  const float* aW2   = (const float*)d_in[9];
  const float* ab2   = (const float*)d_in[10];
  const float* uWih  = (const float*)d_in[11];
  const float* uWhh  = (const float*)d_in[12];
  const float* ubih  = (const float*)d_in[13];
  const float* ubhh  = (const float*)d_in[14];

  const int B = in_sizes[0] / H;            // 1024
  const int T = in_sizes[1] / in_sizes[0];  // 200

  // workspace layout
  char*  ws    = (char*)d_ws;
  f16*   wf    = (f16*)ws;                                  // 393216 B
  int*   lenp  = (int*)(ws + 393216);                       // 4096 B
  float* attb  = (float*)(ws + 397312);                     // B*T*4 = 819200
  f16*   hist  = (f16*)(ws + 1216512);                      // B*T*H*2 = 52428800
  f16*   ubf16 = (f16*)(ws + 1216512 + 52428800);           // B*T*H*2 = 52428800

  prep_weights<<<(4 * G3 * H + 255) / 256, 256, 0, stream>>>(gWih, gWhh, uWih, uWhh, wf);
  prep_len<<<(B + 255) / 256, 256, 0, stream>>>(mask, lenp, T, B);
  prep_cvt<<<2048, 256, 0, stream>>>(ub, ubf16, B * T * H / 8);

  scan_kernel<false><<<B / 16, 512, 0, stream>>>(
      ubf16, wf, wf + G3 * H, gbih, gbhh,
      (const float*)nullptr, (const int*)nullptr, hist, (float*)nullptr, T);

  attn_kernel<<<B, 256, 0, stream>>>(query, hist, mask, aW1, ab1, aW2, ab2, attb, T);

  scan_kernel<true><<<B / 16, 512, 0, stream>>>(
      hist, wf + 2 * G3 * H, wf + 3 * G3 * H, ubih, ubhh,
      attb, lenp, (f16*)nullptr, (float*)d_out, T);
}

// Round 16
// 367.373 us; speedup vs baseline: 1.7775x; 1.2076x over previous
//
#include <hip/hip_runtime.h>

typedef _Float16 f16;
typedef _Float16 f16x8 __attribute__((ext_vector_type(8)));
typedef _Float16 f16x4 __attribute__((ext_vector_type(4)));
typedef float    f32x4 __attribute__((ext_vector_type(4)));

#define H  128
#define G3 384
#define AH 36
#define PADW 136   // padded LDS row: 136 f16 = 272B

// v_rcp_f32 (~1 ulp) instead of IEEE division (proven R10: -100µs total)
__device__ __forceinline__ float sigmoidf_(float x){
  return __builtin_amdgcn_rcpf(1.f + __expf(-x));
}
__device__ __forceinline__ float tanhf_(float x){
  return fmaf(2.f, __builtin_amdgcn_rcpf(1.f + __expf(-2.f*x)), -1.f);
}

// LDS-only barrier: drain LDS ops, then s_barrier. Global prefetch loads
// stay in flight across it.
__device__ __forceinline__ void lds_sync(){
  asm volatile("s_waitcnt lgkmcnt(0)" ::: "memory");
  __builtin_amdgcn_s_barrier();
  asm volatile("" ::: "memory");
}

// ---------------- prep: weights fp32 -> fp16, lengths ----------------
__global__ void prep_weights(const float* __restrict__ a, const float* __restrict__ b,
                             const float* __restrict__ c, const float* __restrict__ d,
                             f16* __restrict__ dst)
{
  int i = blockIdx.x * 256 + threadIdx.x;
  if (i >= 4 * G3 * H) return;
  int m = i / (G3 * H), j = i % (G3 * H);
  const float* s = (m == 0) ? a : (m == 1) ? b : (m == 2) ? c : d;
  dst[i] = (f16)s[j];
}

__global__ void prep_len(const int* __restrict__ mask, int* __restrict__ len, int T, int B)
{
  int b = blockIdx.x * 256 + threadIdx.x;
  if (b >= B) return;
  int s = 0;
  for (int t = 0; t < T; ++t) s += (mask[(size_t)b * T + t] > 0);
  len[b] = s;
}

// ---------------- fused GRU / AUGRU scan (R10 optimum) ----------------
template<bool AUG>
__global__ __launch_bounds__(512)
__attribute__((amdgpu_waves_per_eu(2, 2)))
void scan_kernel(const float* __restrict__ xf32,  // GRU input  [B,T,H] f32
                 const f16*   __restrict__ xf16,  // AUGRU input (hist) [B,T,H] f16
                 const f16*   __restrict__ Wih,   // [3H][H] f16
                 const f16*   __restrict__ Whh,   // [3H][H] f16
                 const float* __restrict__ bih,
                 const float* __restrict__ bhh,
                 const float* __restrict__ att,   // [B,T] (AUG)
                 const int*   __restrict__ len,   // [B]   (AUG)
                 f16*         __restrict__ histo, // [B,T,H] f16 (GRU)
                 float*       __restrict__ outp,  // [B,H]       (AUG)
                 int T)
{
  __shared__ f16  xs[2][16 * PADW];
  __shared__ f16  hs[2][16 * PADW];

  const int tid = threadIdx.x;
  const int w   = tid >> 6;
  const int l   = tid & 63;
  const int l16 = l & 15;
  const int lhi = l >> 4;
  const int b0  = blockIdx.x * 16;
  const int colb = w * 16;
  const int c4   = colb + lhi * 4;
  const int srow = tid >> 5, cc = tid & 31;

  // Weight fragments (24 x f16x8 = 96 regs), pinned.
  f16x8 wih[3][4], whh[3][4];
  #pragma unroll
  for (int g = 0; g < 3; ++g)
    #pragma unroll
    for (int q = 0; q < 4; ++q) {
      int off = (g * H + colb + l16) * H + q * 32 + lhi * 8;
      wih[g][q] = *(const f16x8*)(Wih + off);
      whh[g][q] = *(const f16x8*)(Whh + off);
    }
  #pragma unroll
  for (int g = 0; g < 3; ++g)
    #pragma unroll
    for (int q = 0; q < 4; ++q)
      asm volatile("" : "+v"(wih[g][q]), "+v"(whh[g][q]));

  // bias vectors for the lane's 4 cols (accumulator init)
  f32x4 bR  = *(const f32x4*)(bih + c4);
  { f32x4 t2 = *(const f32x4*)(bhh + c4);      bR  += t2; }
  f32x4 bZ  = *(const f32x4*)(bih + H + c4);
  { f32x4 t2 = *(const f32x4*)(bhh + H + c4);  bZ  += t2; }
  f32x4 bXn = *(const f32x4*)(bih + 2*H + c4);
  f32x4 bHn = *(const f32x4*)(bhh + 2*H + c4);

  float hold[4] = {0.f, 0.f, 0.f, 0.f};
  int len_l = 0;
  if (AUG) len_l = len[b0 + l16];

  // hoisted LDS pointers
  const f16* xrd0 = &xs[0][l16 * PADW + lhi * 8];
  const f16* xrd1 = &xs[1][l16 * PADW + lhi * 8];
  const f16* hrd0 = &hs[0][l16 * PADW + lhi * 8];
  const f16* hrd1 = &hs[1][l16 * PADW + lhi * 8];
  f16* hwr0 = &hs[0][l16 * PADW + c4];
  f16* hwr1 = &hs[1][l16 * PADW + c4];
  f16* xst0 = &xs[0][srow * PADW + cc * 4];
  f16* xst1 = &xs[1][srow * PADW + cc * 4];

  // running global pointers
  const float* pxA32 = xf32 ? (xf32 + ((size_t)(b0 + srow) * T) * H + cc * 4) : nullptr;
  const f16*   pxA16 = xf16 ? (xf16 + ((size_t)(b0 + srow) * T) * H + cc * 4) : nullptr;
  const float* attB  = AUG ? (att + (size_t)(b0 + l16) * T) : nullptr;
  f16*         histp = (!AUG && histo) ? (histo + ((size_t)(b0 + l16) * T) * H + c4) : nullptr;
  float*       outpp = AUG ? (outp + (size_t)(b0 + l16) * H + c4) : nullptr;

  // prologue: zero h buf 0, stage x_0, prefetch x_1 into Pa
  {
    f16x4 z4 = {(f16)0, (f16)0, (f16)0, (f16)0};
    *(f16x4*)(&hs[0][srow * PADW + cc * 4]) = z4;
    if (AUG) {
      f16x4 v = *(const f16x4*)(pxA16);
      *(f16x4*)xst0 = v;
    } else {
      f32x4 v = *(const f32x4*)(pxA32);
      f16x4 h4 = {(f16)v.x, (f16)v.y, (f16)v.z, (f16)v.w};
      *(f16x4*)xst0 = h4;
    }
  }
  f32x4 Pa32 = {0,0,0,0}, Pb32 = {0,0,0,0};
  f16x4 Pa16 = {(f16)0,(f16)0,(f16)0,(f16)0}, Pb16 = Pa16;
  float Aa = 0.f, Ab = 0.f;
  if (AUG) {
    Pa16 = *(const f16x4*)(pxA16 + H);
    Aa = attB[0];
    if (T > 1) Ab = attB[1];
  } else {
    Pa32 = *(const f32x4*)(pxA32 + H);
  }
  const float* pxE32 = pxA32 ? pxA32 + 2 * H : nullptr;
  const float* pxO32 = pxA32 ? pxA32 + 3 * H : nullptr;
  const f16*   pxE16 = pxA16 ? pxA16 + 2 * H : nullptr;
  const f16*   pxO16 = pxA16 ? pxA16 + 3 * H : nullptr;
  lds_sync();

#define STEP(targ_, XRD, HRD, HWRN, XSTN, PW32, PL32, PW16, PL16, AW, PXP32, PXP16) \
  {                                                                            \
    const int t5_  = (targ_);                                                  \
    float at_ = 0.f;                                                           \
    if (AUG) at_ = AW;                                                         \
    if (t5_ + 2 < T) {                                                         \
      if (AUG) {                                                               \
        PL16 = *(const f16x4*)(PXP16);  PXP16 += 2 * H;                        \
        AW = attB[t5_ + 2];                                                    \
      } else {                                                                 \
        PL32 = *(const f32x4*)(PXP32);  PXP32 += 2 * H;                        \
      }                                                                        \
    }                                                                          \
    f16x8 xb[4], hb[4];                                                        \
    _Pragma("unroll")                                                          \
    for (int q = 0; q < 4; ++q) {                                              \
      xb[q] = *(const f16x8*)(XRD + q * 32);                                   \
      hb[q] = *(const f16x8*)(HRD + q * 32);                                   \
    }                                                                          \
    f32x4 aR = bR, aZ = bZ, aXn = bXn, aHn = bHn;                              \
    _Pragma("unroll")                                                          \
    for (int q = 0; q < 4; ++q) {                                              \
      aR  = __builtin_amdgcn_mfma_f32_16x16x32_f16(wih[0][q], xb[q], aR, 0,0,0);  \
      aZ  = __builtin_amdgcn_mfma_f32_16x16x32_f16(wih[1][q], xb[q], aZ, 0,0,0);  \
      aXn = __builtin_amdgcn_mfma_f32_16x16x32_f16(wih[2][q], xb[q], aXn,0,0,0);  \
      aHn = __builtin_amdgcn_mfma_f32_16x16x32_f16(whh[2][q], hb[q], aHn,0,0,0);  \
    }                                                                          \
    _Pragma("unroll")                                                          \
    for (int q = 0; q < 4; ++q) {                                              \
      aR  = __builtin_amdgcn_mfma_f32_16x16x32_f16(whh[0][q], hb[q], aR, 0,0,0);  \
      aZ  = __builtin_amdgcn_mfma_f32_16x16x32_f16(whh[1][q], hb[q], aZ, 0,0,0);  \
    }                                                                          \
    float hn_[4];                                                              \
    _Pragma("unroll")                                                          \
    for (int i = 0; i < 4; ++i) {                                              \
      float r = sigmoidf_(aR[i]);                                              \
      float z = sigmoidf_(aZ[i]);                                              \
      float n = tanhf_(aXn[i] + r * aHn[i]);                                   \
      float h;                                                                 \
      if (AUG) { float u = z * at_; h = hold[i] + u * (n - hold[i]); }         \
      else     { h = n + z * (hold[i] - n); }                                  \
      hold[i] = h; hn_[i] = h;                                                 \
    }                                                                          \
    f16x4 hv = {(f16)hn_[0], (f16)hn_[1], (f16)hn_[2], (f16)hn_[3]};           \
    *(f16x4*)(HWRN) = hv;                                                      \
    if (!AUG) {                                                                \
      *(f16x4*)histp = hv;  histp += H;                                        \
    } else {                                                                   \
      if (t5_ == len_l - 1) {                                                  \
        f32x4 ov = {hn_[0], hn_[1], hn_[2], hn_[3]};                           \
        *(f32x4*)outpp = ov;                                                   \
      }                                                                        \
    }                                                                          \
    if (t5_ + 1 < T) {                                                         \
      if (AUG) {                                                               \
        *(f16x4*)(XSTN) = PW16;                                                \
      } else {                                                                 \
        f16x4 s4 = {(f16)PW32.x, (f16)PW32.y, (f16)PW32.z, (f16)PW32.w};       \
        *(f16x4*)(XSTN) = s4;                                                  \
      }                                                                        \
    }                                                                          \
    lds_sync();                                                                \
  }

  for (int t = 0; t < T; t += 2) {
    STEP(t,     xrd0, hrd0, hwr1, xst1, Pa32, Pb32, Pa16, Pb16, Aa, pxE32, pxE16)
    STEP(t + 1, xrd1, hrd1, hwr0, xst0, Pb32, Pa32, Pb16, Pa16, Ab, pxO32, pxO16)
  }
#undef STEP
}

// ---------------- DIN attention (MFMA version; rcp sigmoid) ----------------
__global__ __launch_bounds__(256)
void attn_kernel(const float* __restrict__ query,
                 const f16*   __restrict__ hist,
                 const int*   __restrict__ mask,
                 const float* __restrict__ W1, const float* __restrict__ b1,
                 const float* __restrict__ W2, const float* __restrict__ b2,
                 float* __restrict__ attv, int T)
{
  __shared__ float qs[H];
  __shared__ f16   WqH[48 * PADW];
  __shared__ float qcp[48], w2p[48];
  __shared__ float logitsS[224];
  __shared__ float red[256];

  const int tid = threadIdx.x, b = blockIdx.x;
  const int w = tid >> 6, l = tid & 63, l16 = l & 15, lhi = l >> 4;

  if (tid < H) qs[tid] = query[b * H + tid];
  if (tid < 48) w2p[tid] = (tid < AH) ? W2[tid] : 0.f;
  __syncthreads();

  for (int i = tid; i < 48 * H; i += 256) {
    int u = i >> 7, k = i & (H - 1);
    float v = 0.f;
    if (u < AH) {
      const float* r = W1 + u * 4 * H;
      v = r[H + k] - r[2*H + k] + qs[k] * r[3*H + k];
    }
    WqH[u * PADW + k] = (f16)v;
  }
  if (tid < 48) {
    float s = 0.f;
    if (tid < AH) {
      const float* r = W1 + tid * 4 * H;
      s = b1[tid];
      for (int k = 0; k < H; ++k) s += qs[k] * (r[k] + r[2*H + k]);
    }
    qcp[tid] = s;
  }
  __syncthreads();

  const f32x4 qcv0 = *(const f32x4*)&qcp[lhi*4];
  const f32x4 qcv1 = *(const f32x4*)&qcp[16 + lhi*4];
  const f32x4 qcv2 = *(const f32x4*)&qcp[32 + lhi*4];
  const f32x4 w2v0 = *(const f32x4*)&w2p[lhi*4];
  const f32x4 w2v1 = *(const f32x4*)&w2p[16 + lhi*4];
  const f32x4 w2v2 = *(const f32x4*)&w2p[32 + lhi*4];

  const int NMT = (T + 15) >> 4;
  for (int mt = w; mt < NMT; mt += 4) {
    const int t0 = mt * 16;
    f16x8 hbf[4];
    #pragma unroll
    for (int q = 0; q < 4; ++q)
      hbf[q] = *(const f16x8*)(hist + ((size_t)b*T + t0 + l16)*H + q*32 + lhi*8);
    f32x4 d0 = {0,0,0,0}, d1 = {0,0,0,0}, d2 = {0,0,0,0};
    #pragma unroll
    for (int q = 0; q < 4; ++q) {
      f16x8 wq0 = *(const f16x8*)(&WqH[ l16       * PADW + q*32 + lhi*8]);
      f16x8 wq1 = *(const f16x8*)(&WqH[(16 + l16) * PADW + q*32 + lhi*8]);
      f16x8 wq2 = *(const f16x8*)(&WqH[(32 + l16) * PADW + q*32 + lhi*8]);
      d0 = __builtin_amdgcn_mfma_f32_16x16x32_f16(wq0, hbf[q], d0, 0,0,0);
      d1 = __builtin_amdgcn_mfma_f32_16x16x32_f16(wq1, hbf[q], d1, 0,0,0);
      d2 = __builtin_amdgcn_mfma_f32_16x16x32_f16(wq2, hbf[q], d2, 0,0,0);
    }
    float p = 0.f;
    #pragma unroll
    for (int i = 0; i < 4; ++i) {
      p += w2v0[i] * sigmoidf_(d0[i] + qcv0[i]);
      p += w2v1[i] * sigmoidf_(d1[i] + qcv1[i]);
      p += w2v2[i] * sigmoidf_(d2[i] + qcv2[i]);
    }
    p += __shfl_xor(p, 16, 64);
    p += __shfl_xor(p, 32, 64);
    if (lhi == 0) logitsS[t0 + l16] = p;
  }
  __syncthreads();

  const int t = tid;
  float logit = -1e30f; int mk = 0;
  if (t < T) {
    mk = mask[(size_t)b*T + t];
    logit = (mk > 0) ? (logitsS[t] + b2[0]) : -1e30f;
  }
  red[tid] = logit; __syncthreads();
  for (int s = 128; s > 0; s >>= 1) { if (tid < s) red[tid] = fmaxf(red[tid], red[tid+s]); __syncthreads(); }
  float mx = red[0]; __syncthreads();
  float ev = (t < T && mk > 0) ? __expf(logit - mx) : 0.f;
  red[tid] = ev; __syncthreads();
  for (int s = 128; s > 0; s >>= 1) { if (tid < s) red[tid] += red[tid+s]; __syncthreads(); }
  float sm = red[0];
  if (t < T) attv[(size_t)b*T + t] = ev * __builtin_amdgcn_rcpf(sm);
}

// ---------------- host ----------------
extern "C" void kernel_launch(void* const* d_in, const int* in_sizes, int n_in,
                              void* d_out, int out_size, void* d_ws, size_t ws_size,
                              hipStream_t stream)
{
  const float* query = (const float*)d_in[0];
  const float* ub    = (const float*)d_in[1];
  const int*   mask  = (const int*)d_in[2];
  const float* gWih  = (const float*)d_in[3];
  const float* gWhh  = (const float*)d_in[4];
  const float* gbih  = (const float*)d_in[5];
  const float* gbhh  = (const float*)d_in[6];
  const float* aW1   = (const float*)d_in[7];
  const float* ab1   = (const float*)d_in[8];
  const float* aW2   = (const float*)d_in[9];
  const float* ab2   = (const float*)d_in[10];
  const float* uWih  = (const float*)d_in[11];
  const float* uWhh  = (const float*)d_in[12];
  const float* ubih  = (const float*)d_in[13];
  const float* ubhh  = (const float*)d_in[14];

  const int B = in_sizes[0] / H;            // 1024
  const int T = in_sizes[1] / in_sizes[0];  // 200

  // workspace layout
  char*  ws   = (char*)d_ws;
  f16*   wf   = (f16*)ws;                                   // 393216 B
  int*   lenp = (int*)(ws + 393216);                        // 4096 B
  float* attb = (float*)(ws + 397312);                      // B*T*4
  f16*   hist = (f16*)(ws + 397312 + (size_t)B * 200 * 4);  // B*T*H f16

  prep_weights<<<(4 * G3 * H + 255) / 256, 256, 0, stream>>>(gWih, gWhh, uWih, uWhh, wf);
  prep_len<<<(B + 255) / 256, 256, 0, stream>>>(mask, lenp, T, B);

  scan_kernel<false><<<B / 16, 512, 0, stream>>>(
      ub, (const f16*)nullptr, wf, wf + G3 * H, gbih, gbhh,
      (const float*)nullptr, (const int*)nullptr, hist, (float*)nullptr, T);

  attn_kernel<<<B, 256, 0, stream>>>(query, hist, mask, aW1, ab1, aW2, ab2, attb, T);

  scan_kernel<true><<<B / 16, 512, 0, stream>>>(
      (const float*)nullptr, hist, wf + 2 * G3 * H, wf + 3 * G3 * H, ubih, ubhh,
      attb, lenp, (f16*)nullptr, (float*)d_out, T);
}